// Round 1
// baseline (1632.298 us; speedup 1.0000x reference)
//
#include <hip/hip_runtime.h>
#include <hip/hip_bf16.h>
#include <math.h>

typedef unsigned short u16;
typedef __bf16 bf16x8 __attribute__((ext_vector_type(8)));
typedef float f32x4 __attribute__((ext_vector_type(4)));

#define B_  2
#define S_  2048
#define D_  4096
#define H_  32
#define HD_ 128

__device__ __forceinline__ unsigned rne_bf16(float x) {
  unsigned u = __float_as_uint(x);
  return (u + 0x7fffu + ((u >> 16) & 1u)) >> 16;
}

__device__ __forceinline__ void async16(void* lds_p, const void* g) {
  __builtin_amdgcn_global_load_lds(
      (__attribute__((address_space(1))) void*)(g),
      (__attribute__((address_space(3))) void*)(lds_p), 16, 0, 0);
}

// ---------------------------------------------------------------- convert
__global__ __launch_bounds__(256) void convert_bf16(
    const float* __restrict__ src, u16* __restrict__ dst, int n8) {
  int i = blockIdx.x * 256 + threadIdx.x;
  if (i >= n8) return;
  const float4* s = (const float4*)src + (size_t)i * 2;
  float4 a = s[0], b = s[1];
  uint4 o;
  o.x = rne_bf16(a.x) | (rne_bf16(a.y) << 16);
  o.y = rne_bf16(a.z) | (rne_bf16(a.w) << 16);
  o.z = rne_bf16(b.x) | (rne_bf16(b.y) << 16);
  o.w = rne_bf16(b.z) | (rne_bf16(b.w) << 16);
  ((uint4*)dst)[i] = o;
}

// ---------------------------------------------------------------- GEMM
// 256x256 tile, BK=64, 8 waves (2x4), 8-phase schedule with counted vmcnt
// (T1 XCD swizzle + T2 LDS XOR swizzle + T3/T4 phases + T5 setprio).
// A row-major MxK, B row-major NxK, C = A*B^T.
//
// LDS (u16 units): buf p at p*32768; A tile [256][64] at +0 (halves of 8192),
// B tile at +16384. Chunk k (16B) of row r stored at slot k^(r&7) (T2);
// global source is inverse-swizzled so global_load_lds dest stays linear.
//
// Schedule per K-tile pair {kt even (buf0), kt+1 (buf1)} — phases each:
//   [ds_reads (next phase's frags)] [stage 1 half-tile] [s_barrier]
//   [lgkmcnt(0)+sched_barrier] [setprio1; 16 MFMA; setprio0] [vmcnt?] [s_barrier]
// Quadrant order (mh,nh): (0,0)(0,1)(1,1)(1,0). Reads: C1:B[nh1](kt),
// C2:A[mh1](kt), C3:A[mh0](kt+1), C4:B[nh0](kt+1). Stage stream per tile t:
// Bh1@prev.C1, Bh0@C2, Ah0@C3, Ah1@C4 (each region read-free >=1 barrier
// before its rewrite is issued). vmcnt(4) at C2/C3 ends: every awaited load
// was issued >=2 phases earlier; never drained to 0 in the main loop.

#define WGBAR() asm volatile("s_barrier" ::: "memory")
#define LGKM0() do { asm volatile("s_waitcnt lgkmcnt(0)" ::: "memory"); \
                     __builtin_amdgcn_sched_barrier(0); } while (0)
#define VMW(N)  asm volatile("s_waitcnt vmcnt(" #N ")" ::: "memory")

#define STAGE_A(P, HH, T) do { \
  async16(&lds[(P) * 32768 + (HH) * 8192 + c0 * 8], Ag[HH][0] + (size_t)(T) * 64); \
  async16(&lds[(P) * 32768 + (HH) * 8192 + c1 * 8], Ag[HH][1] + (size_t)(T) * 64); \
} while (0)
#define STAGE_B(P, HH, T) do { \
  async16(&lds[(P) * 32768 + 16384 + (HH) * 8192 + c0 * 8], Bg[HH][0] + (size_t)(T) * 64); \
  async16(&lds[(P) * 32768 + 16384 + (HH) * 8192 + c1 * 8], Bg[HH][1] + (size_t)(T) * 64); \
} while (0)

#define READ_A(dst, P, MH) do { \
  _Pragma("unroll") for (int i_ = 0; i_ < 4; ++i_) \
  _Pragma("unroll") for (int kk_ = 0; kk_ < 2; ++kk_) \
    dst[i_][kk_] = *(const bf16x8*)&lds[(P) * 32768 + ((MH) * 4 + i_) * 1024 + aoff[kk_]]; \
} while (0)
#define READ_B(dst, P, NH) do { \
  _Pragma("unroll") for (int j_ = 0; j_ < 2; ++j_) \
  _Pragma("unroll") for (int kk_ = 0; kk_ < 2; ++kk_) \
    dst[j_][kk_] = *(const bf16x8*)&lds[(P) * 32768 + ((NH) * 2 + j_) * 1024 + boff[kk_]]; \
} while (0)

#define MFMA_Q(AF, BF, IB, JB) do { \
  __builtin_amdgcn_s_setprio(1); \
  _Pragma("unroll") for (int kk_ = 0; kk_ < 2; ++kk_) \
  _Pragma("unroll") for (int i_ = 0; i_ < 4; ++i_) \
  _Pragma("unroll") for (int j_ = 0; j_ < 2; ++j_) \
    acc[(IB) + i_][(JB) + j_] = __builtin_amdgcn_mfma_f32_16x16x32_bf16( \
        AF[i_][kk_], BF[j_][kk_], acc[(IB) + i_][(JB) + j_], 0, 0, 0); \
  __builtin_amdgcn_s_setprio(0); \
} while (0)

template <int MODE>
__global__ __launch_bounds__(512, 2) void gemm_bt(
    const u16* __restrict__ A, const u16* __restrict__ Bw,
    u16* __restrict__ outB, float* __restrict__ outF,
    const float* __restrict__ fc, const float* __restrict__ fs) {
  __shared__ __align__(16) u16 lds[65536];  // 128 KiB

  const int tid = threadIdx.x;
  const int lane = tid & 63;
  const int w = tid >> 6;
  const int lm = lane & 15, quad = lane >> 4;
  const int wr = w >> 2, wc = w & 3;
  const int K = 4096;
  const int NKT = K / 64;  // 64

  // T1: bijective XCD swizzle (256 wgs, 8 XCDs -> 32 contiguous each)
  const int bid = blockIdx.x;
  const int swz = (bid & 7) * 32 + (bid >> 3);
  const int m0 = (swz >> 4) * 256, n0 = (swz & 15) * 256;

  // ---- staging pointers (inverse-swizzled global source, linear LDS dest)
  const int c0 = tid, c1 = tid + 512;
  const int rl0 = c0 >> 3, s0 = ((c0 & 7) ^ (rl0 & 7)) * 8;
  const int rl1 = c1 >> 3, s1 = ((c1 & 7) ^ (rl1 & 7)) * 8;
  const u16* Ag[2][2];
  const u16* Bg[2][2];
#pragma unroll
  for (int hh = 0; hh < 2; ++hh) {
    Ag[hh][0] = A + (size_t)(m0 + hh * 128 + rl0) * K + s0;
    Ag[hh][1] = A + (size_t)(m0 + hh * 128 + rl1) * K + s1;
    Bg[hh][0] = Bw + (size_t)(n0 + hh * 128 + rl0) * K + s0;
    Bg[hh][1] = Bw + (size_t)(n0 + hh * 128 + rl1) * K + s1;
  }

  // ---- frag read offsets (u16 units), swizzled slot = (kk*4+quad)^(lm&7)
  int aoff[2], boff[2];
#pragma unroll
  for (int kk = 0; kk < 2; ++kk) {
    const int sw = ((kk * 4 + quad) ^ (lm & 7)) * 8;
    aoff[kk] = (wr * 128 + lm) * 64 + sw;
    boff[kk] = 16384 + (wc * 64 + lm) * 64 + sw;
  }

  bf16x8 aA[4][2], aB[4][2], b0r[2][2], b1r[2][2];
  f32x4 acc[8][4] = {};

  // ---- prologue: kt0 full (4 ht) + kt1 {Bh0, Ah0, Ah1}; 14 loads in flight
  STAGE_A(0, 0, 0); STAGE_A(0, 1, 0); STAGE_B(0, 0, 0); STAGE_B(0, 1, 0);
  STAGE_B(1, 0, 1); STAGE_A(1, 0, 1); STAGE_A(1, 1, 1);
  VMW(6);   // kt0's 8 loads complete; kt1's 3 ht stay in flight
  WGBAR();
  READ_A(aA, 0, 0);   // A[mh0] kt0
  READ_B(b0r, 0, 0);  // B[nh0] kt0

  for (int kt = 0; kt < NKT - 2; kt += 2) {
    // ======== tile kt (buf0): aA=mh0(kt), b0r=nh0(kt)
    // C1
    READ_B(b1r, 0, 1);            // nh1(kt)
    STAGE_B(1, 1, kt + 1);        // (kt+1).Bh1
    WGBAR(); LGKM0();
    MFMA_Q(aA, b0r, 0, 0);
    WGBAR();
    // C2
    READ_A(aB, 0, 1);             // mh1(kt)
    STAGE_B(0, 0, kt + 2);        // (kt+2).Bh0
    WGBAR(); LGKM0();
    MFMA_Q(aA, b1r, 0, 2);
    VMW(4);                       // completes (kt+1).Ah1 and older
    WGBAR();
    // C3
    READ_A(aA, 1, 0);             // mh0(kt+1) from buf1
    STAGE_A(0, 0, kt + 2);        // (kt+2).Ah0
    WGBAR(); LGKM0();
    MFMA_Q(aB, b1r, 4, 2);
    VMW(4);                       // completes (kt+1).Bh1 and older
    WGBAR();
    // C4
    READ_B(b1r, 1, 0);            // nh0(kt+1) from buf1
    STAGE_A(0, 1, kt + 2);        // (kt+2).Ah1
    WGBAR(); LGKM0();
    MFMA_Q(aB, b0r, 4, 0);
    WGBAR();
    // ======== tile kt+1 (buf1): aA=mh0(kt+1), b1r=nh0(kt+1)
    // C1'
    READ_B(b0r, 1, 1);            // nh1(kt+1)
    STAGE_B(0, 1, kt + 2);        // (kt+2).Bh1
    WGBAR(); LGKM0();
    MFMA_Q(aA, b1r, 0, 0);
    WGBAR();
    // C2'
    READ_A(aB, 1, 1);             // mh1(kt+1)
    STAGE_B(1, 0, kt + 3);        // (kt+3).Bh0
    WGBAR(); LGKM0();
    MFMA_Q(aA, b0r, 0, 2);
    VMW(4);                       // completes (kt+2).Ah1 and older
    WGBAR();
    // C3'
    READ_A(aA, 0, 0);             // mh0(kt+2) from buf0
    STAGE_A(1, 0, kt + 3);        // (kt+3).Ah0
    WGBAR(); LGKM0();
    MFMA_Q(aB, b0r, 4, 2);
    VMW(4);                       // completes (kt+2).Bh1 and older
    WGBAR();
    // C4'
    READ_B(b0r, 0, 0);            // nh0(kt+2) from buf0
    STAGE_A(1, 1, kt + 3);        // (kt+3).Ah1
    WGBAR(); LGKM0();
    MFMA_Q(aB, b1r, 4, 0);
    WGBAR();
  }

  // ======== tail: tile 62 (buf0) — only (63).Bh1 left to stage
  READ_B(b1r, 0, 1);
  STAGE_B(1, 1, NKT - 1);
  WGBAR(); LGKM0();
  MFMA_Q(aA, b0r, 0, 0);
  WGBAR();
  READ_A(aB, 0, 1);
  WGBAR(); LGKM0();
  MFMA_Q(aA, b1r, 0, 2);
  VMW(2);                         // completes (63).Ah1
  WGBAR();
  READ_A(aA, 1, 0);
  WGBAR(); LGKM0();
  MFMA_Q(aB, b1r, 4, 2);
  VMW(0);                         // completes (63).Bh1
  WGBAR();
  READ_B(b1r, 1, 0);
  WGBAR(); LGKM0();
  MFMA_Q(aB, b0r, 4, 0);
  WGBAR();
  // ======== tail: tile 63 (buf1)
  READ_B(b0r, 1, 1);
  WGBAR(); LGKM0();
  MFMA_Q(aA, b1r, 0, 0);
  WGBAR();
  READ_A(aB, 1, 1);
  WGBAR(); LGKM0();
  MFMA_Q(aA, b0r, 0, 2);
  WGBAR();
  MFMA_Q(aB, b0r, 4, 2);
  MFMA_Q(aB, b1r, 4, 0);

  // ---------------- epilogues (per wave: rows m0+wr*128+i*16+quad*4+r,
  //                               cols n0+wc*64+j*16+lm)
  if (MODE == 1) {  // RoPE -> [bh][s][d] bf16
#pragma unroll
    for (int i = 0; i < 8; ++i) {
      const int mbase = m0 + wr * 128 + i * 16 + quad * 4;
#pragma unroll
      for (int j = 0; j < 4; ++j) {
        const int n = n0 + wc * 64 + j * 16 + lm;
        const int hh = n >> 7, d = n & 127, ir = d >> 1;
#pragma unroll
        for (int r = 0; r < 4; ++r) {
          const int m = mbase + r;
          const int s = m & (S_ - 1);
          const int bb = m >> 11;
          float v = acc[i][j][r];
          float p = __shfl_xor(v, 1);
          float cv = fc[s * (HD_ / 2) + ir];
          float sv = fs[s * (HD_ / 2) + ir];
          float o = ((lane & 1) == 0) ? (v * cv - p * sv) : (p * sv + v * cv);
          float po = __shfl_xor(o, 1);
          if ((lane & 1) == 0) {
            unsigned pkt = rne_bf16(o) | (rne_bf16(po) << 16);
            size_t idx = (((size_t)(bb * H_ + hh) * S_ + s) * HD_ + d) >> 1;
            ((unsigned*)outB)[idx] = pkt;
          }
        }
      }
    }
  } else if (MODE == 3) {  // V^T -> [bh][d][s] bf16
#pragma unroll
    for (int i = 0; i < 8; ++i) {
      const int mbase = m0 + wr * 128 + i * 16 + quad * 4;
      const int sB = mbase & (S_ - 1);
      const int bb = mbase >> 11;
#pragma unroll
      for (int j = 0; j < 4; ++j) {
        const int n = n0 + wc * 64 + j * 16 + lm;
        const int hh = n >> 7, d = n & 127;
        uint2 pkt;
        pkt.x = rne_bf16(acc[i][j][0]) | (rne_bf16(acc[i][j][1]) << 16);
        pkt.y = rne_bf16(acc[i][j][2]) | (rne_bf16(acc[i][j][3]) << 16);
        size_t idx = ((size_t)(bb * H_ + hh) * HD_ + d) * S_ + sB;
        *(uint2*)&outB[idx] = pkt;
      }
    }
  } else {  // fp32 out [m][n]
#pragma unroll
    for (int i = 0; i < 8; ++i) {
      const int mbase = m0 + wr * 128 + i * 16 + quad * 4;
#pragma unroll
      for (int j = 0; j < 4; ++j) {
        const int n = n0 + wc * 64 + j * 16 + lm;
#pragma unroll
        for (int r = 0; r < 4; ++r) outF[(size_t)(mbase + r) * D_ + n] = acc[i][j][r];
      }
    }
  }
}

// ---------------------------------------------------------------- flash attention v3
// (unchanged this round) S^T formulation, Q frags in registers, BQ=128, BK=64.
__global__ __launch_bounds__(256, 2) void flash_attn(
    const u16* __restrict__ Qb, const u16* __restrict__ Kb,
    const u16* __restrict__ Vtb, u16* __restrict__ attn) {
  __shared__ __align__(16) u16 lds[32768];

  const int tid = threadIdx.x;
  const int lane = tid & 63, w = tid >> 6;
  const int lm = lane & 15, quad = lane >> 4;
  const int qb = 15 - blockIdx.x;
  const int bh = blockIdx.y;
  const int bb = bh >> 5, h = bh & 31;

  const u16* Qg = Qb + ((size_t)bh * S_ + qb * 128 + w * 32) * HD_;
  const u16* Kg = Kb + (size_t)bh * S_ * HD_;
  const u16* Vg = Vtb + (size_t)bh * HD_ * S_;

  const u16* kp[4];
  const u16* vp[4];
#pragma unroll
  for (int it = 0; it < 4; ++it) {
    int c = tid + 256 * it;
    int kr = c >> 4, kc = (c & 15) ^ (kr & 15);
    kp[it] = Kg + (size_t)kr * HD_ + kc * 8;
    int vr = c >> 3, vc = (c & 7) ^ (vr & 7);
    vp[it] = Vg + (size_t)vr * S_ + vc * 8;
  }

  bf16x8 qf[2][4];
#pragma unroll
  for (int qt = 0; qt < 2; ++qt)
#pragma unroll
    for (int dk = 0; dk < 4; ++dk)
      qf[qt][dk] = *(const bf16x8*)(Qg + (size_t)(qt * 16 + lm) * HD_ + dk * 32 + quad * 8);

  f32x4 accO[8][2] = {};
  float m_run[2] = {-1e30f, -1e30f}, l_run[2] = {0.f, 0.f};
  const float scale = 0.08838834764831845f;
  const int nkt = 2 * qb + 2;
  const int qg0 = qb * 128 + w * 32;
  const int wq_max = qg0 + 31;

#pragma unroll
  for (int it = 0; it < 4; ++it) {
    async16(&lds[(tid + 256 * it) * 8], kp[it]);
    async16(&lds[8192 + (tid + 256 * it) * 8], vp[it]);
  }

  for (int kt = 0; kt < nkt; ++kt) {
    const int k0 = kt * 64;
    const int cur = (kt & 1) * 16384;
    __syncthreads();
    if (kt + 1 < nkt) {
      const int nxt = cur ^ 16384;
      const size_t koK = (size_t)(kt + 1) * 64 * HD_;
      const size_t koV = (size_t)(kt + 1) * 64;
#pragma unroll
      for (int it = 0; it < 4; ++it) {
        async16(&lds[nxt + (tid + 256 * it) * 8], kp[it] + koK);
        async16(&lds[nxt + 8192 + (tid + 256 * it) * 8], vp[it] + koV);
      }
    }
    if (k0 <= wq_max) {
      const u16* Ks = lds + cur;
      const u16* Vts = lds + cur + 8192;
      f32x4 sacc[2][4] = {};
#pragma unroll
      for (int dk = 0; dk < 4; ++dk) {
        bf16x8 kf[4];
#pragma unroll
        for (int t = 0; t < 4; ++t) {
          int row = (t >> 1) * 32 + ((lm >> 2) * 8) + ((t & 1) * 4) + (lm & 3);
          int ch = (dk * 4 + quad) ^ (row & 15);
          kf[t] = *(const bf16x8*)&Ks[(row * 16 + ch) * 8];
        }
#pragma unroll
        for (int t = 0; t < 4; ++t)
#pragma unroll
          for (int qt = 0; qt < 2; ++qt)
            sacc[qt][t] = __builtin_amdgcn_mfma_f32_16x16x32_bf16(kf[t], qf[qt][dk], sacc[qt][t], 0, 0, 0);
      }
      if (k0 + 63 > qg0) {
#pragma unroll
        for (int qt = 0; qt < 2; ++qt) {
          int q = qg0 + qt * 16 + lm;
#pragma unroll
          for (int t = 0; t < 4; ++t) {
            int kb = k0 + (t >> 1) * 32 + quad * 8 + (t & 1) * 4;
#pragma unroll
            for (int r = 0; r < 4; ++r)
              if (kb + r > q) sacc[qt][t][r] = -1e30f;
          }
        }
      }
      bf16x8 pf[2][2];
      float alpha[2];
#pragma unroll
      for (int qt = 0; qt < 2; ++qt) {
        float tmax = sacc[qt][0][0];
#pragma unroll
        for (int t = 0; t < 4; ++t)
#pragma unroll
          for (int r = 0; r < 4; ++r) tmax = fmaxf(tmax, sacc[qt][t][r]);
        tmax = fmaxf(tmax, __shfl_xor(tmax, 16));
        tmax = fmaxf(tmax, __shfl_xor(tmax, 32));
        float mnew = fmaxf(m_run[qt], tmax);
        alpha[qt] = __expf((m_run[qt] - mnew) * scale);
        m_run[qt] = mnew;
        float ms = mnew * scale;
        float rs = 0.f;
#pragma unroll
        for (int t = 0; t < 4; ++t)
#pragma unroll
          for (int r = 0; r < 4; ++r) {
            float p = __expf(fmaf(sacc[qt][t][r], scale, -ms));
            sacc[qt][t][r] = p;
            rs += p;
          }
        rs += __shfl_xor(rs, 16);
        rs += __shfl_xor(rs, 32);
        l_run[qt] = l_run[qt] * alpha[qt] + rs;
#pragma unroll
        for (int kc = 0; kc < 2; ++kc)
#pragma unroll
          for (int j = 0; j < 4; ++j) {
            pf[kc][qt][j]     = (__bf16)sacc[qt][2 * kc][j];
            pf[kc][qt][j + 4] = (__bf16)sacc[qt][2 * kc + 1][j];
          }
      }
#pragma unroll
      for (int dt = 0; dt < 8; ++dt)
#pragma unroll
        for (int qt = 0; qt < 2; ++qt)
#pragma unroll
          for (int r = 0; r < 4; ++r) accO[dt][qt][r] *= alpha[qt];
#pragma unroll
      for (int kc = 0; kc < 2; ++kc)
#pragma unroll
        for (int dt = 0; dt < 8; ++dt) {
          int row = dt * 16 + lm;
          int ch = (kc * 4 + quad) ^ (row & 7);
          bf16x8 vf = *(const bf16x8*)&Vts[(row * 8 + ch) * 8];
#pragma unroll
          for (int qt = 0; qt < 2; ++qt)
            accO[dt][qt] = __builtin_amdgcn_mfma_f32_16x16x32_bf16(vf, pf[kc][qt], accO[dt][qt], 0, 0, 0);
        }
    }
  }

  __syncthreads();
  u16* Et = lds;
  float inv[2] = {1.f / l_run[0], 1.f / l_run[1]};
#pragma unroll
  for (int dt = 0; dt < 8; ++dt)
#pragma unroll
    for (int qt = 0; qt < 2; ++qt) {
      const int rowq = w * 32 + qt * 16 + lm;
#pragma unroll
      for (int rp = 0; rp < 2; ++rp) {
        float a0 = accO[dt][qt][rp * 2] * inv[qt];
        float a1 = accO[dt][qt][rp * 2 + 1] * inv[qt];
        unsigned pkt = rne_bf16(a0) | (rne_bf16(a1) << 16);
        *(unsigned*)&Et[rowq * 136 + dt * 16 + quad * 4 + rp * 2] = pkt;
      }
    }
  const int rloc = w * 32 + (lane >> 1);
  const int half = lane & 1;
  const size_t gbase = (size_t)(bb * S_ + qb * 128 + rloc) * D_ + h * 128 + half * 64;
#pragma unroll
  for (int k = 0; k < 8; ++k) {
    uint4 vv = *(const uint4*)&Et[rloc * 136 + half * 64 + k * 8];
    *(uint4*)&attn[gbase + k * 8] = vv;
  }
}

// ---------------------------------------------------------------- launch
extern "C" void kernel_launch(void* const* d_in, const int* in_sizes, int n_in,
                              void* d_out, int out_size, void* d_ws, size_t ws_size,
                              hipStream_t stream) {
  const float* x  = (const float*)d_in[0];
  const float* fc = (const float*)d_in[1];
  const float* fs = (const float*)d_in[2];
  // d_in[3] = mask (causal, handled analytically)
  const float* wq = (const float*)d_in[4];
  const float* wk = (const float*)d_in[5];
  const float* wv = (const float*)d_in[6];
  const float* wo = (const float*)d_in[7];
  float* out = (float*)d_out;

  char* ws = (char*)d_ws;
  const size_t SZ = (size_t)B_ * S_ * D_ * 2;
  u16* xb  = (u16*)(ws);
  u16* wqb = (u16*)(ws + SZ);
  u16* wkb = (u16*)(ws + 2 * SZ);
  u16* wvb = (u16*)(ws + 3 * SZ);
  u16* Qb  = (u16*)(ws + 4 * SZ);
  u16* Kb  = (u16*)(ws + 5 * SZ);
  u16* Vtb = (u16*)(ws + 6 * SZ);
  u16* attn = xb;
  u16* wob  = wqb;

  dim3 blk(256);
  const int n8 = (B_ * S_ * D_) / 8;
  convert_bf16<<<n8 / 256, blk, 0, stream>>>(x, xb, n8);
  convert_bf16<<<n8 / 256, blk, 0, stream>>>(wq, wqb, n8);
  convert_bf16<<<n8 / 256, blk, 0, stream>>>(wk, wkb, n8);
  convert_bf16<<<n8 / 256, blk, 0, stream>>>(wv, wvb, n8);

  dim3 blkG(512);
  dim3 g1(256);
  gemm_bt<1><<<g1, blkG, 0, stream>>>(xb, wqb, Qb, nullptr, fc, fs);
  gemm_bt<1><<<g1, blkG, 0, stream>>>(xb, wkb, Kb, nullptr, fc, fs);
  gemm_bt<3><<<g1, blkG, 0, stream>>>(xb, wvb, Vtb, nullptr, nullptr, nullptr);

  dim3 g2(16, 64);
  flash_attn<<<g2, blk, 0, stream>>>(Qb, Kb, Vtb, attn);

  convert_bf16<<<n8 / 256, blk, 0, stream>>>(wo, wob, n8);
  gemm_bt<4><<<g1, blkG, 0, stream>>>(attn, wob, nullptr, out, nullptr, nullptr);
}

// Round 2
// 1125.574 us; speedup vs baseline: 1.4502x; 1.4502x over previous
//
#include <hip/hip_runtime.h>
#include <hip/hip_bf16.h>
#include <math.h>

typedef unsigned short u16;
typedef __bf16 bf16x8 __attribute__((ext_vector_type(8)));
typedef float f32x4 __attribute__((ext_vector_type(4)));

#define B_  2
#define S_  2048
#define D_  4096
#define H_  32
#define HD_ 128

__device__ __forceinline__ unsigned rne_bf16(float x) {
  unsigned u = __float_as_uint(x);
  return (u + 0x7fffu + ((u >> 16) & 1u)) >> 16;
}

__device__ __forceinline__ void async16(void* lds_p, const void* g) {
  __builtin_amdgcn_global_load_lds(
      (__attribute__((address_space(1))) void*)(g),
      (__attribute__((address_space(3))) void*)(lds_p), 16, 0, 0);
}

// ---------------------------------------------------------------- convert
__global__ __launch_bounds__(256) void convert_bf16(
    const float* __restrict__ src, u16* __restrict__ dst, int n8) {
  int i = blockIdx.x * 256 + threadIdx.x;
  if (i >= n8) return;
  const float4* s = (const float4*)src + (size_t)i * 2;
  float4 a = s[0], b = s[1];
  uint4 o;
  o.x = rne_bf16(a.x) | (rne_bf16(a.y) << 16);
  o.y = rne_bf16(a.z) | (rne_bf16(a.w) << 16);
  o.z = rne_bf16(b.x) | (rne_bf16(b.y) << 16);
  o.w = rne_bf16(b.z) | (rne_bf16(b.w) << 16);
  ((uint4*)dst)[i] = o;
}

// ---------------------------------------------------------------- GEMM
// 128x128 tile, BK=32, 256 thr (4 waves), m97-class structure upgraded with
// DOUBLE-BUFFERED LDS + one-step prefetch: stage tile t+1 BEFORE reads/MFMA
// of tile t; single __syncthreads() per K-step (its vmcnt(0)/lgkmcnt(0)
// drain lands a full compute-phase after the stage issue). 32 KB LDS ->
// 3 blocks/CU (implicit m114 overlap preserved).
// LDS chunk swizzle: slot s of row r holds global 16B-chunk s^((r>>1)&3)
// (pre-swizzled global source keeps global_load_lds dest linear; reads use
// the same XOR). A row-major MxK, B row-major NxK, C = A*B^T.
template <int MODE>
__global__ __launch_bounds__(256, 3) void gemm_bt(
    const u16* __restrict__ A, const u16* __restrict__ Bw,
    u16* __restrict__ outB, float* __restrict__ outF,
    const float* __restrict__ fc, const float* __restrict__ fs) {
  // buf p at p*8192 (u16): A tile 128x32 at +0, B tile at +4096. 32 KB total.
  __shared__ __align__(16) u16 lds[16384];
  const int tid  = threadIdx.x;
  const int lane = tid & 63;
  const int wave = tid >> 6;
  const int lm   = lane & 15, quad = lane >> 4;
  const int mr = (wave >> 1) * 64, nc = (wave & 1) * 64;
  const int K = 4096;
  const int NT = K / 32;  // 128 K-steps

  // XCD-aware 2D-blocked swizzle: 32x32 tile grid; XCD x owns an 8-row x
  // 16-col rectangle (rows (x&3)*8.., cols (x>>2)*16..). Bijective.
  const int bid = blockIdx.y * 32 + blockIdx.x;
  const int xg = bid & 7, l = bid >> 3;
  const int m0 = (((xg & 3) * 8) + (l & 7)) * 128;
  const int n0 = (((xg >> 2) * 16) + (l >> 3)) * 128;

  // staging: 512 16B-chunks per tile per matrix; thread covers chunks
  // ca=tid, cb=tid+256. chunk c: row=c>>2, lds slot=c&3, global chunk
  // g=(c&3)^((c>>3)&3)  [ (4r+s)>>3 == r>>1 for s<4 ]
  const int ca = tid, cb = tid + 256;
  const int ra = ca >> 2, ga = ((ca & 3) ^ ((ca >> 3) & 3)) * 8;
  const int rb = cb >> 2, gb = ((cb & 3) ^ ((cb >> 3) & 3)) * 8;
  const u16* Ag0 = A + (size_t)(m0 + ra) * K + ga;
  const u16* Ag1 = A + (size_t)(m0 + rb) * K + gb;
  const u16* Bg0 = Bw + (size_t)(n0 + ra) * K + ga;
  const u16* Bg1 = Bw + (size_t)(n0 + rb) * K + gb;

  // frag read: row r=base+lm, want global chunk quad -> slot quad^((r>>1)&3);
  // base is a multiple of 16 so (r>>1)&3 == (lm>>1)&3 (bank-floor spread).
  const int koff = (quad ^ ((lm >> 1) & 3)) * 8;

  f32x4 acc[4][4] = {};

  // prologue: stage tile 0 into buf 0
  async16(&lds[ca * 8], Ag0);
  async16(&lds[cb * 8], Ag1);
  async16(&lds[4096 + ca * 8], Bg0);
  async16(&lds[4096 + cb * 8], Bg1);
  __syncthreads();

  for (int t = 0; t < NT; ++t) {
    const u16* As = lds + (t & 1) * 8192;
    const u16* Bs = As + 4096;
    if (t < NT - 1) {  // prefetch t+1 into the other buffer (issue-early)
      u16* Ld = lds + ((t + 1) & 1) * 8192;
      const size_t ko = (size_t)(t + 1) * 32;
      async16(&Ld[ca * 8], Ag0 + ko);
      async16(&Ld[cb * 8], Ag1 + ko);
      async16(&Ld[4096 + ca * 8], Bg0 + ko);
      async16(&Ld[4096 + cb * 8], Bg1 + ko);
    }
    bf16x8 af[4], bfr[4];
#pragma unroll
    for (int i = 0; i < 4; ++i) af[i] = *(const bf16x8*)&As[(mr + i * 16 + lm) * 32 + koff];
#pragma unroll
    for (int j = 0; j < 4; ++j) bfr[j] = *(const bf16x8*)&Bs[(nc + j * 16 + lm) * 32 + koff];
#pragma unroll
    for (int i = 0; i < 4; ++i)
#pragma unroll
      for (int j = 0; j < 4; ++j)
        acc[i][j] = __builtin_amdgcn_mfma_f32_16x16x32_bf16(af[i], bfr[j], acc[i][j], 0, 0, 0);
    // drains vmcnt(0) (prefetch t+1 landed; issued a full compute-phase ago),
    // lgkmcnt(0), then barrier -> buf[(t+1)&1] ready, buf[t&1] free.
    __syncthreads();
  }

  if (MODE == 1) {  // RoPE -> [bh][s][d]
#pragma unroll
    for (int i = 0; i < 4; ++i) {
      const int mbase = m0 + mr + i * 16 + quad * 4;
#pragma unroll
      for (int j = 0; j < 4; ++j) {
        const int n = n0 + nc + j * 16 + lm;
        const int h = n >> 7, d = n & 127, ir = d >> 1;
#pragma unroll
        for (int r = 0; r < 4; ++r) {
          const int m = mbase + r;
          const int s = m & (S_ - 1);
          const int bb = m >> 11;
          float v = acc[i][j][r];
          float p = __shfl_xor(v, 1);
          float cv = fc[s * (HD_ / 2) + ir];
          float sv = fs[s * (HD_ / 2) + ir];
          float o = ((lane & 1) == 0) ? (v * cv - p * sv) : (p * sv + v * cv);
          float po = __shfl_xor(o, 1);
          if ((lane & 1) == 0) {
            unsigned pkt = rne_bf16(o) | (rne_bf16(po) << 16);
            size_t idx = (((size_t)(bb * H_ + h) * S_ + s) * HD_ + d) >> 1;
            ((unsigned*)outB)[idx] = pkt;
          }
        }
      }
    }
  } else if (MODE == 3) {  // V^T -> [bh][d][s]
#pragma unroll
    for (int i = 0; i < 4; ++i) {
      const int mbase = m0 + mr + i * 16 + quad * 4;
      const int s0 = mbase & (S_ - 1);
      const int bb = mbase >> 11;
#pragma unroll
      for (int j = 0; j < 4; ++j) {
        const int n = n0 + nc + j * 16 + lm;
        const int h = n >> 7, d = n & 127;
        uint2 pkt;
        pkt.x = rne_bf16(acc[i][j][0]) | (rne_bf16(acc[i][j][1]) << 16);
        pkt.y = rne_bf16(acc[i][j][2]) | (rne_bf16(acc[i][j][3]) << 16);
        size_t idx = ((size_t)(bb * H_ + h) * HD_ + d) * S_ + s0;
        *(uint2*)&outB[idx] = pkt;
      }
    }
  } else {  // fp32 out [m][n]
#pragma unroll
    for (int i = 0; i < 4; ++i) {
      const int mbase = m0 + mr + i * 16 + quad * 4;
#pragma unroll
      for (int j = 0; j < 4; ++j) {
        const int n = n0 + nc + j * 16 + lm;
#pragma unroll
        for (int r = 0; r < 4; ++r) outF[(size_t)(mbase + r) * D_ + n] = acc[i][j][r];
      }
    }
  }
}

// ---------------------------------------------------------------- flash attention v3
// (unchanged) S^T formulation, Q frags in registers, BQ=128, BK=64.
__global__ __launch_bounds__(256, 2) void flash_attn(
    const u16* __restrict__ Qb, const u16* __restrict__ Kb,
    const u16* __restrict__ Vtb, u16* __restrict__ attn) {
  __shared__ __align__(16) u16 lds[32768];

  const int tid = threadIdx.x;
  const int lane = tid & 63, w = tid >> 6;
  const int lm = lane & 15, quad = lane >> 4;
  const int qb = 15 - blockIdx.x;
  const int bh = blockIdx.y;
  const int bb = bh >> 5, h = bh & 31;

  const u16* Qg = Qb + ((size_t)bh * S_ + qb * 128 + w * 32) * HD_;
  const u16* Kg = Kb + (size_t)bh * S_ * HD_;
  const u16* Vg = Vtb + (size_t)bh * HD_ * S_;

  const u16* kp[4];
  const u16* vp[4];
#pragma unroll
  for (int it = 0; it < 4; ++it) {
    int c = tid + 256 * it;
    int kr = c >> 4, kc = (c & 15) ^ (kr & 15);
    kp[it] = Kg + (size_t)kr * HD_ + kc * 8;
    int vr = c >> 3, vc = (c & 7) ^ (vr & 7);
    vp[it] = Vg + (size_t)vr * S_ + vc * 8;
  }

  bf16x8 qf[2][4];
#pragma unroll
  for (int qt = 0; qt < 2; ++qt)
#pragma unroll
    for (int dk = 0; dk < 4; ++dk)
      qf[qt][dk] = *(const bf16x8*)(Qg + (size_t)(qt * 16 + lm) * HD_ + dk * 32 + quad * 8);

  f32x4 accO[8][2] = {};
  float m_run[2] = {-1e30f, -1e30f}, l_run[2] = {0.f, 0.f};
  const float scale = 0.08838834764831845f;
  const int nkt = 2 * qb + 2;
  const int qg0 = qb * 128 + w * 32;
  const int wq_max = qg0 + 31;

#pragma unroll
  for (int it = 0; it < 4; ++it) {
    async16(&lds[(tid + 256 * it) * 8], kp[it]);
    async16(&lds[8192 + (tid + 256 * it) * 8], vp[it]);
  }

  for (int kt = 0; kt < nkt; ++kt) {
    const int k0 = kt * 64;
    const int cur = (kt & 1) * 16384;
    __syncthreads();
    if (kt + 1 < nkt) {
      const int nxt = cur ^ 16384;
      const size_t koK = (size_t)(kt + 1) * 64 * HD_;
      const size_t koV = (size_t)(kt + 1) * 64;
#pragma unroll
      for (int it = 0; it < 4; ++it) {
        async16(&lds[nxt + (tid + 256 * it) * 8], kp[it] + koK);
        async16(&lds[nxt + 8192 + (tid + 256 * it) * 8], vp[it] + koV);
      }
    }
    if (k0 <= wq_max) {
      const u16* Ks = lds + cur;
      const u16* Vts = lds + cur + 8192;
      f32x4 sacc[2][4] = {};
#pragma unroll
      for (int dk = 0; dk < 4; ++dk) {
        bf16x8 kf[4];
#pragma unroll
        for (int t = 0; t < 4; ++t) {
          int row = (t >> 1) * 32 + ((lm >> 2) * 8) + ((t & 1) * 4) + (lm & 3);
          int ch = (dk * 4 + quad) ^ (row & 15);
          kf[t] = *(const bf16x8*)&Ks[(row * 16 + ch) * 8];
        }
#pragma unroll
        for (int t = 0; t < 4; ++t)
#pragma unroll
          for (int qt = 0; qt < 2; ++qt)
            sacc[qt][t] = __builtin_amdgcn_mfma_f32_16x16x32_bf16(kf[t], qf[qt][dk], sacc[qt][t], 0, 0, 0);
      }
      if (k0 + 63 > qg0) {
#pragma unroll
        for (int qt = 0; qt < 2; ++qt) {
          int q = qg0 + qt * 16 + lm;
#pragma unroll
          for (int t = 0; t < 4; ++t) {
            int kb = k0 + (t >> 1) * 32 + quad * 8 + (t & 1) * 4;
#pragma unroll
            for (int r = 0; r < 4; ++r)
              if (kb + r > q) sacc[qt][t][r] = -1e30f;
          }
        }
      }
      bf16x8 pf[2][2];
      float alpha[2];
#pragma unroll
      for (int qt = 0; qt < 2; ++qt) {
        float tmax = sacc[qt][0][0];
#pragma unroll
        for (int t = 0; t < 4; ++t)
#pragma unroll
          for (int r = 0; r < 4; ++r) tmax = fmaxf(tmax, sacc[qt][t][r]);
        tmax = fmaxf(tmax, __shfl_xor(tmax, 16));
        tmax = fmaxf(tmax, __shfl_xor(tmax, 32));
        float mnew = fmaxf(m_run[qt], tmax);
        alpha[qt] = __expf((m_run[qt] - mnew) * scale);
        m_run[qt] = mnew;
        float ms = mnew * scale;
        float rs = 0.f;
#pragma unroll
        for (int t = 0; t < 4; ++t)
#pragma unroll
          for (int r = 0; r < 4; ++r) {
            float p = __expf(fmaf(sacc[qt][t][r], scale, -ms));
            sacc[qt][t][r] = p;
            rs += p;
          }
        rs += __shfl_xor(rs, 16);
        rs += __shfl_xor(rs, 32);
        l_run[qt] = l_run[qt] * alpha[qt] + rs;
#pragma unroll
        for (int kc = 0; kc < 2; ++kc)
#pragma unroll
          for (int j = 0; j < 4; ++j) {
            pf[kc][qt][j]     = (__bf16)sacc[qt][2 * kc][j];
            pf[kc][qt][j + 4] = (__bf16)sacc[qt][2 * kc + 1][j];
          }
      }
#pragma unroll
      for (int dt = 0; dt < 8; ++dt)
#pragma unroll
        for (int qt = 0; qt < 2; ++qt)
#pragma unroll
          for (int r = 0; r < 4; ++r) accO[dt][qt][r] *= alpha[qt];
#pragma unroll
      for (int kc = 0; kc < 2; ++kc)
#pragma unroll
        for (int dt = 0; dt < 8; ++dt) {
          int row = dt * 16 + lm;
          int ch = (kc * 4 + quad) ^ (row & 7);
          bf16x8 vf = *(const bf16x8*)&Vts[(row * 8 + ch) * 8];
#pragma unroll
          for (int qt = 0; qt < 2; ++qt)
            accO[dt][qt] = __builtin_amdgcn_mfma_f32_16x16x32_bf16(vf, pf[kc][qt], accO[dt][qt], 0, 0, 0);
        }
    }
  }

  __syncthreads();
  u16* Et = lds;
  float inv[2] = {1.f / l_run[0], 1.f / l_run[1]};
#pragma unroll
  for (int dt = 0; dt < 8; ++dt)
#pragma unroll
    for (int qt = 0; qt < 2; ++qt) {
      const int rowq = w * 32 + qt * 16 + lm;
#pragma unroll
      for (int rp = 0; rp < 2; ++rp) {
        float a0 = accO[dt][qt][rp * 2] * inv[qt];
        float a1 = accO[dt][qt][rp * 2 + 1] * inv[qt];
        unsigned pkt = rne_bf16(a0) | (rne_bf16(a1) << 16);
        *(unsigned*)&Et[rowq * 136 + dt * 16 + quad * 4 + rp * 2] = pkt;
      }
    }
  const int rloc = w * 32 + (lane >> 1);
  const int half = lane & 1;
  const size_t gbase = (size_t)(bb * S_ + qb * 128 + rloc) * D_ + h * 128 + half * 64;
#pragma unroll
  for (int k = 0; k < 8; ++k) {
    uint4 vv = *(const uint4*)&Et[rloc * 136 + half * 64 + k * 8];
    *(uint4*)&attn[gbase + k * 8] = vv;
  }
}

// ---------------------------------------------------------------- launch
extern "C" void kernel_launch(void* const* d_in, const int* in_sizes, int n_in,
                              void* d_out, int out_size, void* d_ws, size_t ws_size,
                              hipStream_t stream) {
  const float* x  = (const float*)d_in[0];
  const float* fc = (const float*)d_in[1];
  const float* fs = (const float*)d_in[2];
  // d_in[3] = mask (causal, handled analytically)
  const float* wq = (const float*)d_in[4];
  const float* wk = (const float*)d_in[5];
  const float* wv = (const float*)d_in[6];
  const float* wo = (const float*)d_in[7];
  float* out = (float*)d_out;

  char* ws = (char*)d_ws;
  const size_t SZ = (size_t)B_ * S_ * D_ * 2;
  u16* xb  = (u16*)(ws);
  u16* wqb = (u16*)(ws + SZ);
  u16* wkb = (u16*)(ws + 2 * SZ);
  u16* wvb = (u16*)(ws + 3 * SZ);
  u16* Qb  = (u16*)(ws + 4 * SZ);
  u16* Kb  = (u16*)(ws + 5 * SZ);
  u16* Vtb = (u16*)(ws + 6 * SZ);
  u16* attn = xb;
  u16* wob  = wqb;

  dim3 blk(256);
  const int n8 = (B_ * S_ * D_) / 8;
  convert_bf16<<<n8 / 256, blk, 0, stream>>>(x, xb, n8);
  convert_bf16<<<n8 / 256, blk, 0, stream>>>(wq, wqb, n8);
  convert_bf16<<<n8 / 256, blk, 0, stream>>>(wk, wkb, n8);
  convert_bf16<<<n8 / 256, blk, 0, stream>>>(wv, wvb, n8);

  dim3 g1(32, 32);
  gemm_bt<1><<<g1, blk, 0, stream>>>(xb, wqb, Qb, nullptr, fc, fs);
  gemm_bt<1><<<g1, blk, 0, stream>>>(xb, wkb, Kb, nullptr, fc, fs);
  gemm_bt<3><<<g1, blk, 0, stream>>>(xb, wvb, Vtb, nullptr, nullptr, nullptr);

  dim3 g2(16, 64);
  flash_attn<<<g2, blk, 0, stream>>>(Qb, Kb, Vtb, attn);

  convert_bf16<<<n8 / 256, blk, 0, stream>>>(wo, wob, n8);
  gemm_bt<4><<<g1, blk, 0, stream>>>(attn, wob, nullptr, out, nullptr, nullptr);
}